// Round 3
// baseline (796.957 us; speedup 1.0000x reference)
//
#include <hip/hip_runtime.h>

typedef __bf16 bf16;
typedef __bf16 bf16_8 __attribute__((ext_vector_type(8)));
typedef __bf16 bf16_4 __attribute__((ext_vector_type(4)));
typedef float f32x4 __attribute__((ext_vector_type(4)));

constexpr int kB = 2, kS = 2048, kD = 1024, kH = 16, kHD = 64;
constexpr int kM = kB * kS;
constexpr int kNT = kS / 64;  // 32 k/q tiles

#define GLOBAL_AS const __attribute__((address_space(1)))
#define LDS_AS __attribute__((address_space(3)))

__device__ __forceinline__ void async_copy16(const bf16* g, bf16* l) {
  __builtin_amdgcn_global_load_lds((GLOBAL_AS unsigned int*)g,
                                   (LDS_AS unsigned int*)l, 16, 0, 0);
}

// ---------------- fp32 -> bf16 converts ----------------
__global__ __launch_bounds__(256) void cvt_act(
    const float4* __restrict__ q, const float4* __restrict__ k,
    const float4* __restrict__ v, bf16* __restrict__ oq,
    bf16* __restrict__ ok, bf16* __restrict__ ov) {
  const float4* src = blockIdx.y == 0 ? q : blockIdx.y == 1 ? k : v;
  bf16* dst = blockIdx.y == 0 ? oq : blockIdx.y == 1 ? ok : ov;
  int i = blockIdx.x * 256 + threadIdx.x;
  float4 x = src[i];
  bf16_4 o = {(bf16)x.x, (bf16)x.y, (bf16)x.z, (bf16)x.w};
  *(bf16_4*)(dst + (size_t)i * 4) = o;
}

__global__ __launch_bounds__(256) void cvt_w(
    const float4* __restrict__ a, const float4* __restrict__ b,
    const float4* __restrict__ c, const float4* __restrict__ d,
    bf16* __restrict__ oa, bf16* __restrict__ ob, bf16* __restrict__ oc,
    bf16* __restrict__ od) {
  int z = blockIdx.y;
  const float4* src = z == 0 ? a : z == 1 ? b : z == 2 ? c : d;
  bf16* dst = z == 0 ? oa : z == 1 ? ob : z == 2 ? oc : od;
  int i = blockIdx.x * 256 + threadIdx.x;
  float4 x = src[i];
  bf16_4 o = {(bf16)x.x, (bf16)x.y, (bf16)x.z, (bf16)x.w};
  *(bf16_4*)(dst + (size_t)i * 4) = o;
}

// ---------------- 128x128 GEMM core: C = A(MxK) * B(NxK)^T ----------------
__device__ __forceinline__ void gemm_core(const bf16* __restrict__ A,
                                          const bf16* __restrict__ Bm,
                                          int m0, int n0,
                                          bf16* ldsA, bf16* ldsB,
                                          f32x4 acc[4][4]) {
  const int t = threadIdx.x;
  const int lane = t & 63, wave = t >> 6;
  const int l16 = lane & 15, quad = lane >> 4;
  const int wm = (wave >> 1) * 64, wn = (wave & 1) * 64;
  const f32x4 z4 = {0.f, 0.f, 0.f, 0.f};
#pragma unroll
  for (int i = 0; i < 4; ++i)
#pragma unroll
    for (int j = 0; j < 4; ++j) acc[i][j] = z4;

  for (int kt = 0; kt < kD; kt += 32) {
#pragma unroll
    for (int rep = 0; rep < 2; ++rep) {
      int q = t + rep * 256;
      int row = q >> 2, cc = q & 3;
      bf16* lbase_a = ldsA + (size_t)(wave * 64 + rep * 256) * 8;
      bf16* lbase_b = ldsB + (size_t)(wave * 64 + rep * 256) * 8;
      async_copy16(A + (size_t)(m0 + row) * kD + kt + cc * 8, lbase_a);
      async_copy16(Bm + (size_t)(n0 + row) * kD + kt + cc * 8, lbase_b);
    }
    __syncthreads();
    bf16_8 af[4], bfr[4];
#pragma unroll
    for (int i = 0; i < 4; ++i)
      af[i] = *(const bf16_8*)(ldsA + (wm + i * 16 + l16) * 32 + quad * 8);
#pragma unroll
    for (int j = 0; j < 4; ++j)
      bfr[j] = *(const bf16_8*)(ldsB + (wn + j * 16 + l16) * 32 + quad * 8);
#pragma unroll
    for (int i = 0; i < 4; ++i)
#pragma unroll
      for (int j = 0; j < 4; ++j)
        acc[i][j] = __builtin_amdgcn_mfma_f32_16x16x32_bf16(af[i], bfr[j],
                                                            acc[i][j], 0, 0, 0);
    __syncthreads();
  }
}

// QKV projection; Q pre-scaled by 1/8; head layout (B,H,S,HD)
__global__ __launch_bounds__(256) void gemm_qkv(
    const bf16* __restrict__ qb, const bf16* __restrict__ kb,
    const bf16* __restrict__ vb, const bf16* __restrict__ wq,
    const bf16* __restrict__ wk, const bf16* __restrict__ wv,
    const float* __restrict__ bq, const float* __restrict__ bk,
    const float* __restrict__ bv, bf16* __restrict__ Qh,
    bf16* __restrict__ Kh, bf16* __restrict__ Vh) {
  __shared__ __align__(16) bf16 ldsA[128 * 32];
  __shared__ __align__(16) bf16 ldsB[128 * 32];
  const bf16 *A, *W;
  const float* bias;
  bf16* Out;
  int z = blockIdx.z;
  if (z == 0) { A = qb; W = wq; bias = bq; Out = Qh; }
  else if (z == 1) { A = kb; W = wk; bias = bk; Out = Kh; }
  else { A = vb; W = wv; bias = bv; Out = Vh; }
  const float scale = (z == 0) ? 0.125f : 1.0f;
  int m0 = blockIdx.x * 128, n0 = blockIdx.y * 128;
  f32x4 acc[4][4];
  gemm_core(A, W, m0, n0, ldsA, ldsB, acc);

  const int t = threadIdx.x, lane = t & 63, wave = t >> 6;
  const int l16 = lane & 15, quad = lane >> 4;
  const int wm = (wave >> 1) * 64, wn = (wave & 1) * 64;
#pragma unroll
  for (int i = 0; i < 4; ++i)
#pragma unroll
    for (int j = 0; j < 4; ++j)
#pragma unroll
      for (int r = 0; r < 4; ++r) {
        int m = m0 + wm + i * 16 + quad * 4 + r;
        int n = n0 + wn + j * 16 + l16;
        float v = (acc[i][j][r] + bias[n]) * scale;
        int b = m >> 11, s = m & (kS - 1);
        int h = n >> 6, hd = n & 63;
        Out[((size_t)(b * kH + h) * kS + s) * kHD + hd] = (bf16)v;
      }
}

// V (B,H,S,HD) -> (B,H,HD,S)
__global__ __launch_bounds__(256) void transpose_v(const bf16* __restrict__ Vh,
                                                   bf16* __restrict__ Vt) {
  __shared__ bf16 tile[64][72];
  const int t = threadIdx.x;
  const int s0 = blockIdx.x * 64, bh = blockIdx.y;
#pragma unroll
  for (int it = 0; it < 2; ++it) {
    int chunk = t + it * 256;
    int s = chunk >> 3, d0 = (chunk & 7) * 8;
    bf16_8 v = *(const bf16_8*)(Vh + ((size_t)bh * kS + s0 + s) * kHD + d0);
#pragma unroll
    for (int j = 0; j < 8; ++j) tile[d0 + j][s] = v[j];
  }
  __syncthreads();
#pragma unroll
  for (int it = 0; it < 2; ++it) {
    int chunk = t + it * 256;
    int d = chunk >> 3, c0 = (chunk & 7) * 8;
    bf16_8 o = *(const bf16_8*)&tile[d][c0];
    *(bf16_8*)(Vt + ((size_t)bh * kHD + d) * kS + s0 + c0) = o;
  }
}

// Output projection, 64x128 tile (512 blocks -> 2/CU)
__global__ __launch_bounds__(256) void gemm_out(const bf16* __restrict__ AO,
                                                const bf16* __restrict__ wo,
                                                const float* __restrict__ bo,
                                                float* __restrict__ Cout) {
  __shared__ __align__(16) bf16 ldsA[64 * 32];
  __shared__ __align__(16) bf16 ldsB[128 * 32];
  const int t = threadIdx.x, lane = t & 63, wave = t >> 6;
  const int l16 = lane & 15, quad = lane >> 4;
  const int wm = (wave >> 1) * 32, wn = (wave & 1) * 64;
  const int m0 = blockIdx.x * 64, n0 = blockIdx.y * 128;
  const f32x4 z4 = {0.f, 0.f, 0.f, 0.f};
  f32x4 acc[2][4];
#pragma unroll
  for (int i = 0; i < 2; ++i)
#pragma unroll
    for (int j = 0; j < 4; ++j) acc[i][j] = z4;

  for (int kt = 0; kt < kD; kt += 32) {
    // rep0: A (256 chunks), rep1/2: B (512 chunks)
    async_copy16(AO + (size_t)(m0 + (t >> 2)) * kD + kt + (t & 3) * 8,
                 ldsA + (size_t)(wave * 64) * 8);
    async_copy16(wo + (size_t)(n0 + (t >> 2)) * kD + kt + (t & 3) * 8,
                 ldsB + (size_t)(wave * 64) * 8);
    {
      int c = t + 256;
      async_copy16(wo + (size_t)(n0 + (c >> 2)) * kD + kt + (c & 3) * 8,
                   ldsB + (size_t)(wave * 64 + 256) * 8);
    }
    __syncthreads();
    bf16_8 af[2], bfr[4];
#pragma unroll
    for (int i = 0; i < 2; ++i)
      af[i] = *(const bf16_8*)(ldsA + (wm + i * 16 + l16) * 32 + quad * 8);
#pragma unroll
    for (int j = 0; j < 4; ++j)
      bfr[j] = *(const bf16_8*)(ldsB + (wn + j * 16 + l16) * 32 + quad * 8);
#pragma unroll
    for (int i = 0; i < 2; ++i)
#pragma unroll
      for (int j = 0; j < 4; ++j)
        acc[i][j] = __builtin_amdgcn_mfma_f32_16x16x32_bf16(af[i], bfr[j],
                                                            acc[i][j], 0, 0, 0);
    __syncthreads();
  }
#pragma unroll
  for (int i = 0; i < 2; ++i)
#pragma unroll
    for (int j = 0; j < 4; ++j)
#pragma unroll
      for (int r = 0; r < 4; ++r) {
        int m = m0 + wm + i * 16 + quad * 4 + r;
        int n = n0 + wn + j * 16 + l16;
        Cout[(size_t)m * kD + n] = acc[i][j][r] + bo[n];
      }
}

// ---------------- attention ----------------
// LDS carve (40 KB): pass2 K0|V0|K1|V1|P (5 x 8KB); pass1 reuses [0,32KB) as
// two 128x64 K tiles. Pass2 has ONE barrier/tile: the ldsP round-trip is
// intra-wave (each wave's strip feeds only its own PV frags + attnW rows).
__global__ __launch_bounds__(256) void attn_kernel(
    const bf16* __restrict__ Qh, const bf16* __restrict__ Kh,
    const bf16* __restrict__ Vt, float* __restrict__ attnW,
    bf16* __restrict__ AO) {
  __shared__ __align__(16) bf16 smem[20480];
  bf16* const Pstrip = smem + 16384;

  const int t = threadIdx.x, lane = t & 63, wave = t >> 6;
  const int l16 = lane & 15, quad = lane >> 4;
  const int bh = blockIdx.x;
  const int qt = (kNT - 1) - blockIdx.y;  // heavy-first
  const int q0 = qt * 64;

  const bf16* Qbase = Qh + ((size_t)bh * kS + q0) * kHD;
  const bf16* Kbase = Kh + (size_t)bh * kS * kHD;
  const bf16* Vtbase = Vt + (size_t)bh * kHD * kS;

  bf16_8 aq0 = *(const bf16_8*)(Qbase + (wave * 16 + l16) * kHD + quad * 8);
  bf16_8 aq1 = *(const bf16_8*)(Qbase + (wave * 16 + l16) * kHD + 32 + quad * 8);

#define ISSUE_BIG(bt, buf)                                                   \
  {                                                                          \
    _Pragma("unroll") for (int rep = 0; rep < 4; ++rep) {                    \
      int c = t + rep * 256;                                                 \
      async_copy16(Kbase + (size_t)((bt)*128 + (c >> 3)) * kHD + (c & 7) * 8,\
                   smem + (buf)*8192 + (size_t)(wave * 64 + rep * 256) * 8); \
    }                                                                        \
  }
#define ISSUE_K2(kt, buf)                                                    \
  {                                                                          \
    _Pragma("unroll") for (int rep = 0; rep < 2; ++rep) {                    \
      int c = t + rep * 256;                                                 \
      async_copy16(Kbase + (size_t)((kt)*64 + (c >> 3)) * kHD + (c & 7) * 8, \
                   smem + (buf)*8192 + (size_t)(wave * 64 + rep * 256) * 8); \
    }                                                                        \
  }
#define ISSUE_V2(kt, buf)                                                    \
  {                                                                          \
    _Pragma("unroll") for (int rep = 0; rep < 2; ++rep) {                    \
      int c = t + rep * 256;                                                 \
      async_copy16(Vtbase + (size_t)(c >> 3) * kS + (kt)*64 + (c & 7) * 8,   \
                   smem + (buf)*8192 + 4096 +                                \
                       (size_t)(wave * 64 + rep * 256) * 8);                 \
    }                                                                        \
  }

  // ---- pass 1: row expsums, 128-row K tiles, fixed-max softmax ----
  float lp[4] = {0.f, 0.f, 0.f, 0.f};
  const int nbig = (qt + 2) >> 1;
  ISSUE_BIG(0, 0);
  for (int bt = 0; bt < nbig; ++bt) {
    __syncthreads();
    if (bt + 1 < nbig) ISSUE_BIG(bt + 1, (bt + 1) & 1);
    const bf16* Kl = smem + (bt & 1) * 8192;
    f32x4 sacc[8];
#pragma unroll
    for (int j = 0; j < 8; ++j) {
      bf16_8 b0 = *(const bf16_8*)(Kl + (j * 16 + l16) * 64 + quad * 8);
      bf16_8 b1 = *(const bf16_8*)(Kl + (j * 16 + l16) * 64 + 32 + quad * 8);
      f32x4 z = {0.f, 0.f, 0.f, 0.f};
      z = __builtin_amdgcn_mfma_f32_16x16x32_bf16(aq0, b0, z, 0, 0, 0);
      z = __builtin_amdgcn_mfma_f32_16x16x32_bf16(aq1, b1, z, 0, 0, 0);
      sacc[j] = z;
    }
    if (bt == nbig - 1) {  // only the last big tile crosses the diagonal
#pragma unroll
      for (int j = 0; j < 8; ++j)
#pragma unroll
        for (int r = 0; r < 4; ++r) {
          int qrow = q0 + wave * 16 + quad * 4 + r;
          int kcol = bt * 128 + j * 16 + l16;
          lp[r] += (kcol > qrow) ? 0.f : __expf(sacc[j][r]);
        }
    } else {
#pragma unroll
      for (int j = 0; j < 8; ++j)
#pragma unroll
        for (int r = 0; r < 4; ++r) lp[r] += __expf(sacc[j][r]);
    }
  }
  __syncthreads();  // all reads of big tiles done before pass-2 DMA reuses LDS
  ISSUE_K2(0, 0);
  ISSUE_V2(0, 0);
  float rl[4];
#pragma unroll
  for (int r = 0; r < 4; ++r) {  // overlap reduction with the DMA above
    float s = lp[r];
#pragma unroll
    for (int off = 1; off < 16; off <<= 1) s += __shfl_xor(s, off, 64);
    rl[r] = 1.0f / s;
  }

  const f32x4 z4 = {0.f, 0.f, 0.f, 0.f};
  f32x4 oacc[4];
#pragma unroll
  for (int d = 0; d < 4; ++d) oacc[d] = z4;

  // ---- pass 2: scores -> P (LDS strip) -> attnW dwordx4 + PV MFMA ----
  for (int kt = 0; kt <= qt; ++kt) {
    __syncthreads();  // publish K/V[kt]; drains prefetch issued last iter
    if (kt < qt) {
      ISSUE_K2(kt + 1, (kt + 1) & 1);
      ISSUE_V2(kt + 1, (kt + 1) & 1);
    }
    const bf16* Kl = smem + (kt & 1) * 8192;
    const bf16* Vl = Kl + 4096;
    f32x4 sacc[4];
#pragma unroll
    for (int j = 0; j < 4; ++j) {
      bf16_8 b0 = *(const bf16_8*)(Kl + (j * 16 + l16) * 64 + quad * 8);
      bf16_8 b1 = *(const bf16_8*)(Kl + (j * 16 + l16) * 64 + 32 + quad * 8);
      f32x4 z = {0.f, 0.f, 0.f, 0.f};
      z = __builtin_amdgcn_mfma_f32_16x16x32_bf16(aq0, b0, z, 0, 0, 0);
      z = __builtin_amdgcn_mfma_f32_16x16x32_bf16(aq1, b1, z, 0, 0, 0);
      sacc[j] = z;
    }
    if (kt == qt) {  // diagonal tile: mask
#pragma unroll
      for (int j = 0; j < 4; ++j)
#pragma unroll
        for (int r = 0; r < 4; ++r) {
          int qrl = wave * 16 + quad * 4 + r;
          int kcol = kt * 64 + j * 16 + l16;
          float p = __expf(sacc[j][r]) * rl[r];
          if (kcol > q0 + qrl) p = 0.f;
          Pstrip[(size_t)qrl * 64 + j * 16 + l16] = (bf16)p;
        }
    } else {
#pragma unroll
      for (int j = 0; j < 4; ++j)
#pragma unroll
        for (int r = 0; r < 4; ++r) {
          int qrl = wave * 16 + quad * 4 + r;
          float p = __expf(sacc[j][r]) * rl[r];
          Pstrip[(size_t)qrl * 64 + j * 16 + l16] = (bf16)p;
        }
    }
    // attnW: each wave reads back its OWN 16x64 strip (intra-wave dep; no
    // barrier) and stores 256B-contiguous dwordx4 runs.
    {
      int row = lane >> 2, c0 = (lane & 3) * 16;
      const bf16* src = Pstrip + (size_t)(wave * 16 + row) * 64 + c0;
      bf16_8 pa = *(const bf16_8*)src;
      bf16_8 pb = *(const bf16_8*)(src + 8);
      float* dst =
          attnW + ((size_t)bh * kS + q0 + wave * 16 + row) * kS + kt * 64 + c0;
      float4 f0 = {(float)pa[0], (float)pa[1], (float)pa[2], (float)pa[3]};
      float4 f1 = {(float)pa[4], (float)pa[5], (float)pa[6], (float)pa[7]};
      float4 f2 = {(float)pb[0], (float)pb[1], (float)pb[2], (float)pb[3]};
      float4 f3 = {(float)pb[4], (float)pb[5], (float)pb[6], (float)pb[7]};
      ((float4*)dst)[0] = f0;
      ((float4*)dst)[1] = f1;
      ((float4*)dst)[2] = f2;
      ((float4*)dst)[3] = f3;
    }
    // PV: A-frags from own strip, B-frags = Vt tile
    bf16_8 ap0 = *(const bf16_8*)(Pstrip + (size_t)(wave * 16 + l16) * 64 + quad * 8);
    bf16_8 ap1 = *(const bf16_8*)(Pstrip + (size_t)(wave * 16 + l16) * 64 + 32 + quad * 8);
#pragma unroll
    for (int dsub = 0; dsub < 4; ++dsub) {
      bf16_8 bv0 = *(const bf16_8*)(Vl + (dsub * 16 + l16) * 64 + quad * 8);
      bf16_8 bv1 = *(const bf16_8*)(Vl + (dsub * 16 + l16) * 64 + 32 + quad * 8);
      oacc[dsub] = __builtin_amdgcn_mfma_f32_16x16x32_bf16(ap0, bv0, oacc[dsub], 0, 0, 0);
      oacc[dsub] = __builtin_amdgcn_mfma_f32_16x16x32_bf16(ap1, bv1, oacc[dsub], 0, 0, 0);
    }
  }

  // zero-fill strict upper-triangle tiles
  for (int kt = qt + 1; kt < kNT; ++kt) {
    const float4 zf = {0.f, 0.f, 0.f, 0.f};
    int row = t >> 2;
    float* dst = attnW + ((size_t)bh * kS + q0 + row) * kS + kt * 64 + (t & 3) * 16;
#pragma unroll
    for (int f = 0; f < 4; ++f) ((float4*)dst)[f] = zf;
  }

  const int b = bh >> 4, h = bh & 15;
#pragma unroll
  for (int dsub = 0; dsub < 4; ++dsub)
#pragma unroll
    for (int r = 0; r < 4; ++r) {
      int qrow = q0 + wave * 16 + quad * 4 + r;
      int d = dsub * 16 + l16;
      AO[((size_t)(b * kS + qrow)) * kD + h * kHD + d] = (bf16)oacc[dsub][r];
    }
#undef ISSUE_BIG
#undef ISSUE_K2
#undef ISSUE_V2
}

extern "C" void kernel_launch(void* const* d_in, const int* in_sizes, int n_in,
                              void* d_out, int out_size, void* d_ws, size_t ws_size,
                              hipStream_t stream) {
  const float* query = (const float*)d_in[0];
  const float* key_t = (const float*)d_in[1];
  const float* value = (const float*)d_in[2];
  const float* Wq = (const float*)d_in[4];
  const float* bq = (const float*)d_in[5];
  const float* Wk = (const float*)d_in[6];
  const float* bk = (const float*)d_in[7];
  const float* Wv = (const float*)d_in[8];
  const float* bv = (const float*)d_in[9];
  const float* Wo = (const float*)d_in[10];
  const float* bo = (const float*)d_in[11];

  float* out = (float*)d_out;
  float* attnW = out + (size_t)kM * kD;

  bf16* qb = (bf16*)d_ws;
  bf16* kb = qb + (size_t)kM * kD;
  bf16* vb = kb + (size_t)kM * kD;
  bf16* Qh = vb + (size_t)kM * kD;
  bf16* Kh = Qh + (size_t)kM * kD;
  bf16* Vh = Kh + (size_t)kM * kD;
  bf16* Vtr = Vh + (size_t)kM * kD;
  bf16* AO = Vtr + (size_t)kM * kD;
  bf16* wqb = AO + (size_t)kM * kD;
  bf16* wkb = wqb + (size_t)kD * kD;
  bf16* wvb = wkb + (size_t)kD * kD;
  bf16* wob = wvb + (size_t)kD * kD;

  const int n4_x = kM * kD / 4;
  const int n4_w = kD * kD / 4;
  cvt_act<<<dim3(n4_x / 256, 3), 256, 0, stream>>>(
      (const float4*)query, (const float4*)key_t, (const float4*)value,
      qb, kb, vb);
  cvt_w<<<dim3(n4_w / 256, 4), 256, 0, stream>>>(
      (const float4*)Wq, (const float4*)Wk, (const float4*)Wv,
      (const float4*)Wo, wqb, wkb, wvb, wob);

  gemm_qkv<<<dim3(kM / 128, kD / 128, 3), 256, 0, stream>>>(
      qb, kb, vb, wqb, wkb, wvb, bq, bk, bv, Qh, Kh, Vh);

  transpose_v<<<dim3(kS / 64, kB * kH), 256, 0, stream>>>(Vh, Vtr);

  attn_kernel<<<dim3(kB * kH, kNT), 256, 0, stream>>>(Qh, Kh, Vtr, attnW, AO);

  gemm_out<<<dim3(kM / 64, kD / 128), 256, 0, stream>>>(AO, wob, bo, out);
}